// Round 2
// baseline (3463.175 us; speedup 1.0000x reference)
//
#include <hip/hip_runtime.h>

// Problem constants
#define BB 2048
#define TT 26
#define DIN 512
#define HH 512
#define EE 256
#define CC 97
#define SS 32
#define XK 1280   // DIN + EE + HH (fused LSTM input width)
#define G4 2048   // 4*H

typedef unsigned short u16;
typedef __bf16 bf16x8 __attribute__((ext_vector_type(8)));
typedef float f32x4 __attribute__((ext_vector_type(4)));

__device__ __forceinline__ float bf2f(u16 u) {
    return __uint_as_float(((unsigned int)u) << 16);
}
__device__ __forceinline__ u16 f2bf(float f) {  // round-to-nearest-even
    unsigned int u = __float_as_uint(f);
    u = u + 0x7FFFu + ((u >> 16) & 1u);
    return (u16)(u >> 16);
}
__device__ __forceinline__ float sigmoidf(float x) { return 1.0f / (1.0f + expf(-x)); }

// ---------------------------------------------------------------------------
// GEMM: C[M,N] = A[M,K] @ W[N,K]^T (+ bias[n]).  M = gridDim.y*64 (must divide).
// 64x64 tile per 256-thread block, 4 waves each computing a 32x32 MFMA patch.
// A: bf16 (u16) row-major, leading dim lda.  W: bf16 [N][K] row-major.
// ---------------------------------------------------------------------------
template <bool OUT_BF16, bool BIAS>
__global__ __launch_bounds__(256) void gemm_bt(
    const u16* __restrict__ A, int lda,
    const u16* __restrict__ W,
    const float* __restrict__ bias,
    void* __restrict__ Cout, int ldc,
    int N, int K)
{
    __shared__ __align__(16) u16 As[64][32];
    __shared__ __align__(16) u16 Ws[64][32];

    const int tid  = threadIdx.x;
    const int lane = tid & 63;
    const int wave = tid >> 6;
    const int m0 = blockIdx.y * 64;
    const int n0 = blockIdx.x * 64;
    const int ar = tid >> 2;          // 0..63 row within tile for staging
    const int ac = (tid & 3) * 8;     // 0,8,16,24 col within K-tile
    const int wm = (wave >> 1) * 32;  // wave's M offset within tile
    const int wn = (wave & 1) * 32;   // wave's N offset within tile
    const int fr = lane & 15;
    const int fq = lane >> 4;

    f32x4 acc[2][2];
    #pragma unroll
    for (int i = 0; i < 2; i++)
        #pragma unroll
        for (int j = 0; j < 2; j++)
            #pragma unroll
            for (int r = 0; r < 4; r++) acc[i][j][r] = 0.0f;

    const bool wvalid = (n0 + ar) < N;
    const u16* Arow = A + (size_t)(m0 + ar) * lda;
    const u16* Wrow = W + (size_t)(n0 + ar) * K;

    for (int k0 = 0; k0 < K; k0 += 32) {
        uint4 av = *(const uint4*)(Arow + k0 + ac);
        uint4 wv = make_uint4(0u, 0u, 0u, 0u);
        if (wvalid) wv = *(const uint4*)(Wrow + k0 + ac);
        *(uint4*)&As[ar][ac] = av;
        *(uint4*)&Ws[ar][ac] = wv;
        __syncthreads();

        bf16x8 af[2], bfr[2];
        #pragma unroll
        for (int mm = 0; mm < 2; mm++)
            af[mm] = *(const bf16x8*)&As[wm + mm * 16 + fr][fq * 8];
        #pragma unroll
        for (int nn = 0; nn < 2; nn++)
            bfr[nn] = *(const bf16x8*)&Ws[wn + nn * 16 + fr][fq * 8];
        #pragma unroll
        for (int mm = 0; mm < 2; mm++)
            #pragma unroll
            for (int nn = 0; nn < 2; nn++)
                acc[mm][nn] = __builtin_amdgcn_mfma_f32_16x16x32_bf16(
                    af[mm], bfr[nn], acc[mm][nn], 0, 0, 0);
        __syncthreads();
    }

    // Epilogue: D col = lane&15, row = (lane>>4)*4 + r  (verified layout)
    #pragma unroll
    for (int nn = 0; nn < 2; nn++) {
        int col = n0 + wn + nn * 16 + fr;
        if (col < N) {
            float bv = BIAS ? bias[col] : 0.0f;
            #pragma unroll
            for (int mm = 0; mm < 2; mm++) {
                int row = m0 + wm + mm * 16 + fq * 4;
                #pragma unroll
                for (int r = 0; r < 4; r++) {
                    float v = acc[mm][nn][r] + bv;
                    if (OUT_BF16)
                        ((u16*)Cout)[(size_t)(row + r) * ldc + col] = f2bf(v);
                    else
                        ((float*)Cout)[(size_t)(row + r) * ldc + col] = v;
                }
            }
        }
    }
}

// ---------------------------------------------------------------------------
// fp32 -> bf16 cast, 4 elements/thread (n must be divisible by 4)
// ---------------------------------------------------------------------------
__global__ __launch_bounds__(256) void cast_f32_bf16(
    const float* __restrict__ src, u16* __restrict__ dst, int n)
{
    int i = (blockIdx.x * 256 + threadIdx.x) * 4;
    if (i < n) {
        float4 v = *(const float4*)(src + i);
        ushort4 o;
        o.x = f2bf(v.x); o.y = f2bf(v.y); o.z = f2bf(v.z); o.w = f2bf(v.w);
        *(ushort4*)(dst + i) = o;
    }
}

// ---------------------------------------------------------------------------
// Build Wcat[n][k] = bf16([W_ih | W_hh]) and bcat = b_ih + b_hh (fp32)
// ---------------------------------------------------------------------------
__global__ __launch_bounds__(256) void build_wcat(
    const float* __restrict__ W_ih, const float* __restrict__ W_hh,
    const float* __restrict__ b_ih, const float* __restrict__ b_hh,
    u16* __restrict__ Wcat, float* __restrict__ bcat)
{
    int i = blockIdx.x * 256 + threadIdx.x;
    if (i < G4 * XK) {
        int n = i / XK, k = i - n * XK;
        float v = (k < DIN + EE) ? W_ih[(size_t)n * (DIN + EE) + k]
                                 : W_hh[(size_t)n * HH + (k - DIN - EE)];
        Wcat[(size_t)i] = f2bf(v);
    }
    if (i < G4) bcat[i] = b_ih[i] + b_hh[i];
}

// Init: c = 0 (fp32), h-region of x' = 0 (bf16 bits)
__global__ __launch_bounds__(256) void init_state(float* __restrict__ c,
                                                  u16* __restrict__ xp)
{
    int i = blockIdx.x * 256 + threadIdx.x;  // < B*H
    if (i < BB * HH) {
        c[i] = 0.0f;
        int b = i >> 9, h = i & (HH - 1);
        xp[(size_t)b * XK + DIN + EE + h] = 0;
    }
}

// ---------------------------------------------------------------------------
// Attention step: e[t] = sum_h tanh(Hp[b,t,h] + ph[b,h]) * w_score[h];
// softmax; context[d] = sum_t alpha[t]*bH16[b,t,d]; write context (bf16) and
// char-embedding (bf16) into x'[b, 0:768].  One 256-thread block per row.
// ---------------------------------------------------------------------------
__global__ __launch_bounds__(256) void attn_step(
    const u16* __restrict__ Hp, const float* __restrict__ ph,
    const float* __restrict__ wscore, const u16* __restrict__ bH16,
    const int* __restrict__ text, const float* __restrict__ emb,
    u16* __restrict__ xp, int s)
{
    const int b = blockIdx.x;
    const int tid = threadIdx.x, lane = tid & 63, wave = tid >> 6;
    __shared__ float e_sm[TT];
    __shared__ float alpha_sm[TT];

    const float* phb = ph + (size_t)b * HH;
    for (int t = wave; t < TT; t += 4) {
        const u16* hp = Hp + ((size_t)b * TT + t) * HH;
        float sum = 0.0f;
        for (int h = lane; h < HH; h += 64)
            sum += tanhf(bf2f(hp[h]) + phb[h]) * wscore[h];
        #pragma unroll
        for (int off = 32; off > 0; off >>= 1) sum += __shfl_down(sum, off);
        if (lane == 0) e_sm[t] = sum;
    }
    __syncthreads();

    if (tid == 0) {
        float mx = e_sm[0];
        for (int t = 1; t < TT; t++) mx = fmaxf(mx, e_sm[t]);
        float ssum = 0.0f;
        for (int t = 0; t < TT; t++) {
            float ev = expf(e_sm[t] - mx);
            alpha_sm[t] = ev;
            ssum += ev;
        }
        float inv = 1.0f / ssum;
        for (int t = 0; t < TT; t++) alpha_sm[t] *= inv;
    }
    __syncthreads();

    for (int d = tid; d < DIN; d += 256) {
        float ctx = 0.0f;
        const u16* bh = bH16 + (size_t)b * TT * DIN + d;
        #pragma unroll
        for (int t = 0; t < TT; t++) ctx += alpha_sm[t] * bf2f(bh[(size_t)t * DIN]);
        xp[(size_t)b * XK + d] = f2bf(ctx);
    }

    int ch = text[b * SS + s];
    const float* e = emb + (size_t)ch * EE;
    for (int j = tid; j < EE; j += 256)
        xp[(size_t)b * XK + DIN + j] = f2bf(e[j]);
}

// ---------------------------------------------------------------------------
// LSTM pointwise: gate order i,f,g,o.  c fp32 persistent; h -> bf16 into x'.
// ---------------------------------------------------------------------------
__global__ __launch_bounds__(256) void lstm_cell(
    const float* __restrict__ gates, float* __restrict__ c,
    u16* __restrict__ xp)
{
    int i = blockIdx.x * 256 + threadIdx.x;  // < B*H
    int b = i >> 9, h = i & (HH - 1);
    const float* g = gates + (size_t)b * G4;
    float ig = sigmoidf(g[h]);
    float fg = sigmoidf(g[HH + h]);
    float gg = tanhf(g[2 * HH + h]);
    float og = sigmoidf(g[3 * HH + h]);
    float cn = fg * c[i] + ig * gg;
    c[i] = cn;
    float hn = og * tanhf(cn);
    xp[(size_t)b * XK + DIN + EE + h] = f2bf(hn);
}

// ---------------------------------------------------------------------------
// Workspace layout (bytes)
// ---------------------------------------------------------------------------
#define BH16_OFF   ((size_t)0)                       // bf16 [B*T, DIN]  54,525,952
#define HP_OFF     ((size_t)54525952)                // bf16 [B*T, H]    54,525,952
#define XP_OFF     ((size_t)109051904)               // bf16 [B, 1280]    5,242,880
#define WCAT_OFF   ((size_t)114294784)               // bf16 [2048,1280]  5,242,880
#define WI2H_OFF   ((size_t)119537664)               // bf16 [512,512]      524,288
#define WH2H_OFF   ((size_t)120061952)               // bf16 [512,512]      524,288
#define WGEN_OFF   ((size_t)120586240)               // bf16 [97,512]pad    131,072
#define BCAT_OFF   ((size_t)120717312)               // f32 [2048]            8,192
#define PH_OFF     ((size_t)120725504)               // f32 [B,512]       4,194,304
#define GATES_OFF  ((size_t)124919808)               // f32 [B,2048]     16,777,216
#define CST_OFF    ((size_t)141697024)               // f32 [B,512]       4,194,304
// total ~145.9 MB

extern "C" void kernel_launch(void* const* d_in, const int* in_sizes, int n_in,
                              void* d_out, int out_size, void* d_ws, size_t ws_size,
                              hipStream_t stream)
{
    const float* batch_H = (const float*)d_in[0];
    const int*   text    = (const int*)d_in[1];
    const float* W_i2h   = (const float*)d_in[2];
    const float* W_h2h   = (const float*)d_in[3];
    const float* b_h2h   = (const float*)d_in[4];
    const float* w_score = (const float*)d_in[5];
    const float* W_ih    = (const float*)d_in[6];
    const float* W_hh    = (const float*)d_in[7];
    const float* b_ih    = (const float*)d_in[8];
    const float* b_hh    = (const float*)d_in[9];
    const float* W_gen   = (const float*)d_in[10];
    const float* b_gen   = (const float*)d_in[11];
    const float* emb     = (const float*)d_in[12];

    char* ws = (char*)d_ws;
    u16*   bH16   = (u16*)(ws + BH16_OFF);
    u16*   Hp     = (u16*)(ws + HP_OFF);
    u16*   xp     = (u16*)(ws + XP_OFF);
    u16*   Wcat   = (u16*)(ws + WCAT_OFF);
    u16*   Wi2h16 = (u16*)(ws + WI2H_OFF);
    u16*   Wh2h16 = (u16*)(ws + WH2H_OFF);
    u16*   Wgen16 = (u16*)(ws + WGEN_OFF);
    float* bcat   = (float*)(ws + BCAT_OFF);
    float* ph     = (float*)(ws + PH_OFF);
    float* gates  = (float*)(ws + GATES_OFF);
    float* cst    = (float*)(ws + CST_OFF);
    float* out    = (float*)d_out;

    // One-time (per call) prep: casts + fused weight build + state init
    cast_f32_bf16<<<dim3((BB * TT * DIN / 4 + 255) / 256), 256, 0, stream>>>(
        batch_H, bH16, BB * TT * DIN);
    cast_f32_bf16<<<dim3((HH * DIN / 4 + 255) / 256), 256, 0, stream>>>(
        W_i2h, Wi2h16, HH * DIN);
    cast_f32_bf16<<<dim3((HH * HH / 4 + 255) / 256), 256, 0, stream>>>(
        W_h2h, Wh2h16, HH * HH);
    cast_f32_bf16<<<dim3((CC * HH / 4 + 255) / 256), 256, 0, stream>>>(
        W_gen, Wgen16, CC * HH);
    build_wcat<<<dim3((G4 * XK + 255) / 256), 256, 0, stream>>>(
        W_ih, W_hh, b_ih, b_hh, Wcat, bcat);
    init_state<<<dim3((BB * HH + 255) / 256), 256, 0, stream>>>(cst, xp);

    // Hp = batch_H @ W_i2h^T   [B*T, H] bf16
    gemm_bt<true, false><<<dim3(HH / 64, (BB * TT) / 64), 256, 0, stream>>>(
        bH16, DIN, Wi2h16, nullptr, Hp, HH, HH, DIN);

    for (int s = 0; s < SS; s++) {
        // ph = h @ W_h2h^T + b_h2h   (fp32)
        gemm_bt<false, true><<<dim3(HH / 64, BB / 64), 256, 0, stream>>>(
            xp + DIN + EE, XK, Wh2h16, b_h2h, ph, HH, HH, HH);

        // attention -> context & char-embedding into x'
        attn_step<<<dim3(BB), 256, 0, stream>>>(Hp, ph, w_score, bH16,
                                                text, emb, xp, s);

        // gates = [context|ce|h] @ [W_ih|W_hh]^T + (b_ih+b_hh)   (fp32)
        gemm_bt<false, true><<<dim3(G4 / 64, BB / 64), 256, 0, stream>>>(
            xp, XK, Wcat, bcat, gates, G4, G4, XK);

        // LSTM pointwise; h (bf16) back into x'
        lstm_cell<<<dim3((BB * HH + 255) / 256), 256, 0, stream>>>(gates, cst, xp);

        // probs[:, s, :] = h @ W_gen^T + b_gen  (fp32, strided into [B,S,C])
        gemm_bt<false, true><<<dim3((CC + 63) / 64, BB / 64), 256, 0, stream>>>(
            xp + DIN + EE, XK, Wgen16, b_gen, out + (size_t)s * CC, SS * CC, CC, HH);
    }
}